// Round 8
// baseline (301.511 us; speedup 1.0000x reference)
//
#include <hip/hip_runtime.h>
#include <math.h>

#define CIN  64
#define CI   16
#define HH   256
#define WWD  256
#define KS   7
#define STR  4
#define LH   64
#define LWD  64
#define LL   4096
#define DIN  784
#define DINP 896     // padded to multiple of 128 (agg N)
#define DKP  832     // DIN padded to multiple of 64 (fc K)
#define DOUT 196
#define DOUTP 256    // padded N for fc / K for score GEMM
#define NB   2
#define YP   258     // padded rows in bTp
#define XP   264     // padded cols in bTp

typedef __attribute__((ext_vector_type(8))) short bf16x8;
typedef __attribute__((ext_vector_type(4))) float f32x4;
typedef __attribute__((ext_vector_type(16))) float f32x16;
typedef __attribute__((ext_vector_type(8))) int i32x8;
typedef __attribute__((ext_vector_type(4))) int i32x4;

__device__ __forceinline__ unsigned short f2bf(float x) {
    unsigned int u = __float_as_uint(x);
    unsigned int r = (u + 0x7FFFu + ((u >> 16) & 1u)) >> 16;
    return (unsigned short)r;
}
__device__ __forceinline__ float bf2f(unsigned short h) {
    return __uint_as_float(((unsigned int)h) << 16);
}

__device__ __forceinline__ void stage16(const void* g, void* l) {
#if defined(__has_builtin)
#if __has_builtin(__builtin_amdgcn_global_load_lds)
    __builtin_amdgcn_global_load_lds(
        (const __attribute__((address_space(1))) unsigned int*)g,
        (__attribute__((address_space(3))) unsigned int*)l, 16, 0, 0);
    return;
#endif
#endif
    *(float4*)l = *(const float4*)g;
}

// XCD-aware bijective swizzle of a flat 1-D grid (total % 8 == 0).
__device__ __forceinline__ void swz_grid(int gx, int gy, int& ib, int& jb, int& zb) {
    int total = gridDim.x;
    int flat = blockIdx.x;
    int s = (flat & 7) * (total >> 3) + (flat >> 3);
    ib = s % gx; int rem = s / gx; jb = rem % gy; zb = rem / gy;
}

// ---- prep: b (fp32 NCHW) -> bTp bf16 [n][y+1][s=ci/8][x+4][j=ci%8], padded -
__global__ __launch_bounds__(256) void k_prep_b(const float* __restrict__ b,
                                                unsigned short* __restrict__ bTp) {
    int blk = blockIdx.x;            // n*YP blocks
    int yy = blk % YP, n = blk / YP;
    int y = yy - 1;
    int tid = threadIdx.x;
    int s = tid >> 5, cq = tid & 31;
    bool yv = (y >= 0 && y < 256);
#pragma unroll
    for (int it = 0; it < 3; it++) {
        int c = it * 32 + cq;
        if (c < 66) {
            int xx0 = c * 4, x0 = xx0 - 4;
            unsigned short h[4][8];
            if (yv && x0 >= 0 && x0 + 3 < 256) {
#pragma unroll
                for (int j = 0; j < 8; j++) {
                    float4 f = *(const float4*)&b[((size_t)(n * 64 + s * 8 + j) * 256 + y) * 256 + x0];
                    h[0][j] = f2bf(f.x); h[1][j] = f2bf(f.y);
                    h[2][j] = f2bf(f.z); h[3][j] = f2bf(f.w);
                }
            } else {
#pragma unroll
                for (int k = 0; k < 4; k++) {
                    int x = x0 + k;
                    bool v = yv && x >= 0 && x < 256;
#pragma unroll
                    for (int j = 0; j < 8; j++)
                        h[k][j] = v ? f2bf(b[((size_t)(n * 64 + s * 8 + j) * 256 + y) * 256 + x])
                                    : (unsigned short)0;
                }
            }
#pragma unroll
            for (int k = 0; k < 4; k++)
                *(uint4*)&bTp[((((size_t)n * YP + yy) * 8 + s) * XP + xx0 + k) * 8] = *(uint4*)h[k];
        }
    }
}

// ---- prep: conv weights -> wbt[t][h][q][co32][j8] bf16 ---------------------
__global__ void k_prep_wb(const float* __restrict__ g_w, const float* __restrict__ th_w,
                          unsigned short* __restrict__ wbt) {
    int i = blockIdx.x * 256 + threadIdx.x;
    if (i >= 18432) return;
    int j = i & 7, co = (i >> 3) & 31, q = (i >> 8) & 3, h = (i >> 10) & 1, t = i >> 11;
    int ci = h * 32 + q * 8 + j;
    float v;
    if (co < 16) v = g_w[((size_t)co * 64 + ci) * 9 + t];
    else         v = (t == 4) ? th_w[(size_t)(co - 16) * 64 + ci] : 0.f;
    wbt[i] = f2bf(v);
}

// ---- prep: fc weights -> bf16 [f][256][832], zero-padded -------------------
__global__ void k_prep_fc(const float* __restrict__ fc1_w, const float* __restrict__ fc2_w,
                          unsigned short* __restrict__ fcwb) {
    int i = blockIdx.x * 256 + threadIdx.x;
    if (i >= 2 * DOUTP * DKP) return;
    int col = i % DKP; int row = (i / DKP) % DOUTP; int f = i / (DKP * DOUTP);
    float v = 0.f;
    if (row < DOUT && col < DIN) v = (f ? fc2_w : fc1_w)[row * DIN + col];
    fcwb[i] = f2bf(v);
}

// ---- MFMA implicit-GEMM conv: bx[n][y][x][co32] ----------------------------
__global__ __launch_bounds__(256) void k_convm(
        const unsigned short* __restrict__ bTp, const unsigned short* __restrict__ wbt,
        const float* __restrict__ g_b, const float* __restrict__ th_b,
        unsigned short* __restrict__ bx) {
    __shared__ unsigned short wb[18432];
    __shared__ unsigned short ti[8 * 3 * 68 * 8];
    int tid = threadIdx.x;
#pragma unroll
    for (int i = 0; i < 9; i++) {
        int c = i * 256 + tid;
        stage16(wbt + (size_t)c * 8, &wb[c * 8]);
    }
    int n = blockIdx.x >> 8, y = blockIdx.x & 255;
    int wave = tid >> 6, lane = tid & 63, lr = lane & 15, q = lane >> 4;
    int m0 = wave * 16;
    float bg = g_b[lr], bt = th_b[lr];
    for (int xs = 0; xs < 4; xs++) {
        __syncthreads();
        int x0 = xs * 64;
#pragma unroll
        for (int i = 0; i < 7; i++) {
            int c = i * 256 + tid;
            if (c < 1632) {
                int s = c / 204; int rem = c % 204; int r = rem / 68; int cc = rem % 68;
                const unsigned short* src =
                    bTp + ((((size_t)n * YP + y + r) * 8 + s) * XP + (x0 + 3 + cc)) * 8;
                stage16(src, &ti[c * 8]);
            }
        }
        __syncthreads();
        f32x4 a0 = {bg, bg, bg, bg}, a1 = {bt, bt, bt, bt};
#pragma unroll
        for (int t = 0; t < 9; t++) {
            int dy = t / 3, dx = t % 3;
#pragma unroll
            for (int h = 0; h < 2; h++) {
                int s = h * 4 + q;
                bf16x8 av = *(const bf16x8*)&ti[(((s * 3 + dy) * 68) + m0 + lr + dx) * 8];
                bf16x8 b0 = *(const bf16x8*)&wb[((((t * 2 + h) * 4 + q) * 32) + lr) * 8];
                bf16x8 b1 = *(const bf16x8*)&wb[((((t * 2 + h) * 4 + q) * 32) + 16 + lr) * 8];
                a0 = __builtin_amdgcn_mfma_f32_16x16x32_bf16(av, b0, a0, 0, 0, 0);
                a1 = __builtin_amdgcn_mfma_f32_16x16x32_bf16(av, b1, a1, 0, 0, 0);
            }
        }
        size_t pb = (((size_t)n * 256 + y) * 256 + x0 + m0 + q * 4);
#pragma unroll
        for (int r = 0; r < 4; r++) {
            bx[(pb + r) * 32 + lr]      = f2bf(a0[r]);
            bx[(pb + r) * 32 + 16 + lr] = f2bf(a1[r]);
        }
    }
}

// ---- thr: 7x7 stride-4 conv from bf16 bTp; wave per output, lane=(s,j)=ci --
__global__ __launch_bounds__(256) void k_thr(
        const unsigned short* __restrict__ bTp, const float* __restrict__ thr_w,
        const float* __restrict__ thr_b, float* __restrict__ thr) {
    __shared__ float w[64 * 49];
    int tid = threadIdx.x;
    for (int i = tid; i < 64 * 49; i += 256) w[i] = thr_w[i];
    __syncthreads();
    int wid = (blockIdx.x << 2) + (tid >> 6);
    int lane = tid & 63;
    int s = lane >> 3, j = lane & 7;
    int n = wid >> 12, l = wid & 4095;
    int lh = (l >> 6), lw = l & 63;
    const float* wl = w + (s * 8 + j) * 49;
    float acc = 0.f;
#pragma unroll
    for (int dy = 0; dy < 7; dy++) {
        int yy = lh * 4 + dy;
        if (yy >= YP) continue;
        const unsigned short* row = bTp + (((size_t)(n * YP + yy) * 8 + s) * XP) * 8;
#pragma unroll
        for (int dx = 0; dx < 7; dx++) {
            int xx = lw * 4 + dx + 3;
            acc = fmaf(bf2f(row[xx * 8 + j]), wl[dy * 7 + dx], acc);
        }
    }
#pragma unroll
    for (int off = 32; off > 0; off >>= 1) acc += __shfl_down(acc, off, 64);
    if (lane == 0) thr[wid] = acc + thr_b[0];
}

// ---- fused patch extraction: bx -> Pb (bf16, [n][l][DKP]) and
// ----                         bx -> piT8 (fp8, [n][DINP][l])
__global__ __launch_bounds__(256) void k_patches(
        const unsigned short* __restrict__ bx,
        unsigned short* __restrict__ Pb, unsigned char* __restrict__ piT8) {
    __shared__ unsigned short sh[7][68][32];     // 30464 B
    int tid = threadIdx.x;
    int blk = blockIdx.x;                        // n*64*4
    int lwg = blk & 3, lh = (blk >> 2) & 63, n = blk >> 8;
    int x0 = lwg * 64 - 1;                       // (lwg*16)*4 - 1
    int y0 = lh * 4 - 1;
    // stage: 7 rows x 68 cols x 32 ci = 1904 chunks of 16B, zero-filled OOB
    for (int it = 0; it < 8; it++) {
        int c = it * 256 + tid;
        if (c < 1904) {
            int q = c & 3, xx = (c >> 2) % 68, r = c / 272;
            int y = y0 + r, x = x0 + xx;
            uint4 v = make_uint4(0u, 0u, 0u, 0u);
            if (y >= 0 && y < 256 && x >= 0 && x < 256)
                v = *(const uint4*)&bx[(((size_t)(n * 256 + y) * 256 + x) * 32) + q * 8];
            *(uint4*)&sh[r][xx][q * 8] = v;
        }
    }
    __syncthreads();
    // emit Pb: 16 l x 104 uint4 (8 bf16 each), d >= DIN zero-padded
    for (int it = 0; it < 7; it++) {
        int idx = it * 256 + tid;
        if (idx < 16 * 104) {
            int lwl = idx / 104, v8 = idx % 104;
            unsigned short o[8];
#pragma unroll
            for (int k = 0; k < 8; k++) {
                int d = v8 * 8 + k;
                unsigned short val = 0;
                if (d < DIN) {
                    int ci = d / 49, t = d % 49, dy = t / 7, dx = t % 7;
                    val = sh[dy][lwl * 4 + dx][ci];
                }
                o[k] = val;
            }
            int l = lh * 64 + lwg * 16 + lwl;
            *(uint4*)&Pb[((size_t)n * LL + l) * DKP + v8 * 8] = *(uint4*)o;
        }
    }
    // emit piT8: for each d (incl. zero pad to DINP), 16 consecutive l bytes
    for (int it = 0; it < 4; it++) {
        int d = it * 256 + tid;
        if (d < DINP) {
            unsigned int w[4] = {0u, 0u, 0u, 0u};
            if (d < DIN) {
                int ci = d / 49, t = d % 49, dy = t / 7, dx = t % 7;
#pragma unroll
                for (int p = 0; p < 4; p++) {
                    float v0 = bf2f(sh[dy][(p * 4 + 0) * 4 + dx][16 + ci]);
                    float v1 = bf2f(sh[dy][(p * 4 + 1) * 4 + dx][16 + ci]);
                    float v2 = bf2f(sh[dy][(p * 4 + 2) * 4 + dx][16 + ci]);
                    float v3 = bf2f(sh[dy][(p * 4 + 3) * 4 + dx][16 + ci]);
                    int a = __builtin_amdgcn_cvt_pk_fp8_f32(v0, v1, 0, false);
                    a     = __builtin_amdgcn_cvt_pk_fp8_f32(v2, v3, a, true);
                    w[p] = (unsigned)a;
                }
            }
            *(uint4*)&piT8[((size_t)n * DINP + d) * LL + lh * 64 + lwg * 16] =
                make_uint4(w[0], w[1], w[2], w[3]);
        }
    }
}

// ---- MFMA GEMM (NT) bf16, depth-2 pipelined (T3+T4), XCD-swizzled: --------
template<int MODE>
__global__ __launch_bounds__(256) void k_gemm_nt(
        const unsigned short* __restrict__ A, const unsigned short* __restrict__ Bt,
        void* __restrict__ C, int lda, int ldb, int ldc, int K,
        size_t sA, size_t sB, size_t sC,
        const float* __restrict__ bias1, const float* __restrict__ bias2,
        int gx, int gy) {
    __shared__ unsigned short lA[2][128 * 64];
    __shared__ unsigned short lB[2][128 * 64];
    int tid = threadIdx.x;
    int wave = tid >> 6, lane = tid & 63;
    int lr = lane & 15, lq = lane >> 4;
    int wm = (wave >> 1) * 64, wn = (wave & 1) * 64;
    int ib, jb, z;
    swz_grid(gx, gy, ib, jb, z);
    int i0 = ib * 128, j0 = jb * 128;
    int az = (MODE == 2) ? (z >> 1) : z;
    int bz = (MODE == 2) ? (z & 1) : z;
    const unsigned short* Ab = A + (size_t)az * sA + (size_t)i0 * lda;
    const unsigned short* Bb = Bt + (size_t)bz * sB + (size_t)j0 * ldb;

    auto stageAB = [&](int buf, int k0) {
#pragma unroll
        for (int it = 0; it < 4; it++) {
            int c = it * 256 + tid;
            int row = c >> 3, slot = c & 7;
            int col8 = slot ^ (row & 7);
            stage16(Ab + (size_t)row * lda + k0 + col8 * 8, &lA[buf][c * 8]);
        }
#pragma unroll
        for (int it = 0; it < 4; it++) {
            int c = it * 256 + tid;
            int row = c >> 3, slot = c & 7;
            int col8 = slot ^ (row & 7);
            stage16(Bb + (size_t)row * ldb + k0 + col8 * 8, &lB[buf][c * 8]);
        }
    };

    f32x4 acc[4][4] = {};
    int NT = K >> 6;
    stageAB(0, 0);
    stageAB(1, 64);
    for (int t = 0; t < NT; ++t) {
        int cur = t & 1;
        if (t + 1 < NT) { asm volatile("s_waitcnt vmcnt(8)" ::: "memory"); }
        else            { asm volatile("s_waitcnt vmcnt(0)" ::: "memory"); }
        __builtin_amdgcn_s_barrier();
#pragma unroll
        for (int ks = 0; ks < 2; ks++) {
            bf16x8 af[4], bfr[4];
#pragma unroll
            for (int t2 = 0; t2 < 4; t2++) {
                int row = wm + t2 * 16 + lr;
                int slot = ks * 4 + lq;
                af[t2] = *(const bf16x8*)&lA[cur][row * 64 + (slot ^ (row & 7)) * 8];
            }
#pragma unroll
            for (int t2 = 0; t2 < 4; t2++) {
                int row = wn + t2 * 16 + lr;
                int slot = ks * 4 + lq;
                bfr[t2] = *(const bf16x8*)&lB[cur][row * 64 + (slot ^ (row & 7)) * 8];
            }
#pragma unroll
            for (int mi = 0; mi < 4; mi++)
#pragma unroll
                for (int nj = 0; nj < 4; nj++)
                    acc[mi][nj] = __builtin_amdgcn_mfma_f32_16x16x32_bf16(
                        af[mi], bfr[nj], acc[mi][nj], 0, 0, 0);
        }
        asm volatile("s_waitcnt lgkmcnt(0)" ::: "memory");
        __builtin_amdgcn_s_barrier();
        if (t + 2 < NT) stageAB(cur, (t + 2) << 6);
    }
    if (MODE == 1) {
        unsigned short* Cb = (unsigned short*)C + (size_t)z * sC;
#pragma unroll
        for (int mi = 0; mi < 4; mi++)
#pragma unroll
            for (int r = 0; r < 4; r++) {
                int row = i0 + wm + mi * 16 + lq * 4 + r;
#pragma unroll
                for (int nj = 0; nj < 4; nj++)
                    Cb[(size_t)row * ldc + j0 + wn + nj * 16 + lr] = f2bf(acc[mi][nj][r]);
            }
    } else {
        const float* biasp = bz ? bias2 : bias1;
        unsigned short* Cb = (unsigned short*)C + (size_t)z * sC;
#pragma unroll
        for (int mi = 0; mi < 4; mi++)
#pragma unroll
            for (int r = 0; r < 4; r++) {
                int row = i0 + wm + mi * 16 + lq * 4 + r;
#pragma unroll
                for (int nj = 0; nj < 4; nj++) {
                    int col = j0 + wn + nj * 16 + lr;
                    float bv = (col < DOUT) ? biasp[col] : 0.f;
                    float v = fmaxf(acc[mi][nj][r] + bv, 0.f);
                    Cb[(size_t)row * ldc + col] = f2bf(v);
                }
            }
    }
}

// ---- MX-fp8 MFMA GEMM (NT), depth-2 pipelined, 256x128 block tile ----------
// 4 waves 2Mx2N; wave tile 128x64 as 4x2 of 32x32x64. LDS 96KB (1 block/CU).
// Wide wave tile cuts LDS reads/FLOP 2.67x vs the 128^2 tile (LDS-port bound).
__global__ __launch_bounds__(256) void k_gemm_mx(
        const unsigned char* __restrict__ A, const unsigned char* __restrict__ Bt,
        unsigned short* __restrict__ C, int lda, int ldb, int ldc, int K,
        size_t sA, size_t sB, size_t sC, int gx, int gy) {
    __shared__ unsigned char lA[2][256 * 128];
    __shared__ unsigned char lB[2][128 * 128];
    int tid = threadIdx.x;
    int wave = tid >> 6, lane = tid & 63;
    int lr = lane & 31, hf = lane >> 5;
    int wm = (wave >> 1) * 128, wn = (wave & 1) * 64;
    int ib, jb, z;
    swz_grid(gx, gy, ib, jb, z);
    int i0 = ib * 256, j0 = jb * 128;
    const unsigned char* Ab = A + (size_t)z * sA + (size_t)i0 * lda;
    const unsigned char* Bb = Bt + (size_t)z * sB + (size_t)j0 * ldb;

    auto stageAB = [&](int buf, int k0) {
#pragma unroll
        for (int it = 0; it < 8; it++) {          // A: 2048 chunks of 16B
            int c = it * 256 + tid;
            int row = c >> 3, slot = c & 7;
            int col16 = slot ^ ((row ^ (row >> 3)) & 7);
            stage16(Ab + (size_t)row * lda + k0 + col16 * 16, &lA[buf][c * 16]);
        }
#pragma unroll
        for (int it = 0; it < 4; it++) {          // B: 1024 chunks of 16B
            int c = it * 256 + tid;
            int row = c >> 3, slot = c & 7;
            int col16 = slot ^ ((row ^ (row >> 3)) & 7);
            stage16(Bb + (size_t)row * ldb + k0 + col16 * 16, &lB[buf][c * 16]);
        }
    };

    f32x16 acc[4][2] = {};
    int NT = K >> 7;
    stageAB(0, 0);
    stageAB(1, 128);
    for (int t = 0; t < NT; ++t) {
        int cur = t & 1;
        // wait for buf[cur]'s 12 per-thread loads; keep next tile's 12 in flight
        if (t + 1 < NT) { asm volatile("s_waitcnt vmcnt(12)" ::: "memory"); }
        else           { asm volatile("s_waitcnt vmcnt(0)" ::: "memory"); }
        __builtin_amdgcn_s_barrier();
        asm volatile("" ::: "memory");
#pragma unroll
        for (int kk = 0; kk < 2; kk++) {          // two K=64 steps
            i32x8 af[4], bfv[2];
            int c0 = kk * 4 + hf * 2;
#pragma unroll
            for (int t2 = 0; t2 < 4; t2++) {
                int row = wm + t2 * 32 + lr;
                int sw = (row ^ (row >> 3)) & 7;
                i32x4 lo = *(const i32x4*)&lA[cur][row * 128 + ((c0    ) ^ sw) * 16];
                i32x4 hi = *(const i32x4*)&lA[cur][row * 128 + ((c0 + 1) ^ sw) * 16];
                af[t2][0] = lo[0]; af[t2][1] = lo[1]; af[t2][2] = lo[2]; af[t2][3] = lo[3];
                af[t2][4] = hi[0]; af[t2][5] = hi[1]; af[t2][6] = hi[2]; af[t2][7] = hi[3];
            }
#pragma unroll
            for (int t2 = 0; t2 < 2; t2++) {
                int row = wn + t2 * 32 + lr;
                int sw = (row ^ (row >> 3)) & 7;
                i32x4 lo = *(const i32x4*)&lB[cur][row * 128 + ((c0    ) ^ sw) * 16];
                i32x4 hi = *(const i32x4*)&lB[cur][row * 128 + ((c0 + 1) ^ sw) * 16];
                bfv[t2][0] = lo[0]; bfv[t2][1] = lo[1]; bfv[t2][2] = lo[2]; bfv[t2][3] = lo[3];
                bfv[t2][4] = hi[0]; bfv[t2][5] = hi[1]; bfv[t2][6] = hi[2]; bfv[t2][7] = hi[3];
            }
#pragma unroll
            for (int mi = 0; mi < 4; mi++)
#pragma unroll
                for (int nj = 0; nj < 2; nj++)
                    acc[mi][nj] = __builtin_amdgcn_mfma_scale_f32_32x32x64_f8f6f4(
                        af[mi], bfv[nj], acc[mi][nj],
                        0, 0,                      // cbsz = fp8(e4m3), blgp = fp8(e4m3)
                        0, 0x7F7F7F7F,             // opsel_a, scale_a = 1.0
                        0, 0x7F7F7F7F);            // opsel_b, scale_b = 1.0
        }
        // all ds_reads of buf[cur] complete before anyone restages into it
        asm volatile("s_waitcnt lgkmcnt(0)" ::: "memory");
        __builtin_amdgcn_s_barrier();
        if (t + 2 < NT) stageAB(cur, (t + 2) << 7);
    }
    unsigned short* Cb = C + (size_t)z * sC;
#pragma unroll
    for (int mi = 0; mi < 4; mi++)
#pragma unroll
        for (int nj = 0; nj < 2; nj++)
#pragma unroll
            for (int reg = 0; reg < 16; reg++) {
                int row = i0 + wm + mi * 32 + (reg & 3) + 8 * (reg >> 2) + 4 * hf;
                int col = j0 + wn + nj * 32 + lr;
                Cb[(size_t)row * ldc + col] = f2bf(acc[mi][nj][reg]);
            }
}

// ---- fused masked-softmax: bf16 score row -> fp8 attn row (regs + shfl) ----
__global__ __launch_bounds__(256) void k_softmax(
        const unsigned short* __restrict__ score, const float* __restrict__ thr,
        unsigned char* __restrict__ attn8) {
    __shared__ float redm[4], reds[4], redn[4];
    int row = blockIdx.x, tid = threadIdx.x;
    int wave = tid >> 6, lane = tid & 63;
    const uint4* g4 = (const uint4*)(score + (size_t)row * LL);
    float t = thr[row];
    uint4 u0 = g4[tid], u1 = g4[tid + 256];
    float v[16];
    {
        unsigned int w[8] = {u0.x, u0.y, u0.z, u0.w, u1.x, u1.y, u1.z, u1.w};
#pragma unroll
        for (int q = 0; q < 8; q++) {
            v[2 * q]     = __uint_as_float(w[q] << 16);
            v[2 * q + 1] = __uint_as_float(w[q] & 0xFFFF0000u);
        }
    }
    float mx = 0.f;
#pragma unroll
    for (int k = 0; k < 16; k++) if (v[k] >= t) mx = fmaxf(mx, v[k]);
#pragma unroll
    for (int off = 32; off > 0; off >>= 1) mx = fmaxf(mx, __shfl_xor(mx, off, 64));
    if (lane == 0) redm[wave] = mx;
    __syncthreads();
    float M = 10.f * fmaxf(fmaxf(fmaxf(redm[0], redm[1]), fmaxf(redm[2], redm[3])), 0.f);
    float e[16];
    float s2 = 0.f, n0 = 0.f;
#pragma unroll
    for (int k = 0; k < 16; k++) {
        if (v[k] >= t) { e[k] = __expf(10.f * v[k] - M); s2 += e[k]; }
        else           { e[k] = 0.f; n0 += 1.f; }
    }
#pragma unroll
    for (int off = 32; off > 0; off >>= 1) {
        s2 += __shfl_xor(s2, off, 64);
        n0 += __shfl_xor(n0, off, 64);
    }
    if (lane == 0) { reds[wave] = s2; redn[wave] = n0; }
    __syncthreads();
    float S2 = (reds[0] + reds[1]) + (reds[2] + reds[3]);
    float N0 = (redn[0] + redn[1]) + (redn[2] + redn[3]);
    float iD = 1.f / (S2 + 1e-8f * (S2 + N0 * __expf(-M)));
#pragma unroll
    for (int i = 0; i < 2; i++) {
        int c = tid + i * 256;
        int d0 = __builtin_amdgcn_cvt_pk_fp8_f32(e[i * 8 + 0] * iD, e[i * 8 + 1] * iD, 0, false);
        d0     = __builtin_amdgcn_cvt_pk_fp8_f32(e[i * 8 + 2] * iD, e[i * 8 + 3] * iD, d0, true);
        int d1 = __builtin_amdgcn_cvt_pk_fp8_f32(e[i * 8 + 4] * iD, e[i * 8 + 5] * iD, 0, false);
        d1     = __builtin_amdgcn_cvt_pk_fp8_f32(e[i * 8 + 6] * iD, e[i * 8 + 7] * iD, d1, true);
        *(uint2*)&attn8[(size_t)row * LL + (size_t)c * 8] = make_uint2((unsigned)d0, (unsigned)d1);
    }
}

// ---- fused fold+final, vectorized: phase 1 gathers zi row into LDS;
// ---- phase 2 does 16->64 conv + residual with float4 streams (1KB/wave).
__global__ __launch_bounds__(256) void k_fold_final(
        const unsigned short* __restrict__ aggb, const float* __restrict__ b,
        const float* __restrict__ W_w, const float* __restrict__ W_b,
        float* __restrict__ out) {
    __shared__ float w[16 * 64];
    __shared__ float zl[16][260];                // padded row: conflict-free
    int tid = threadIdx.x;
    for (int i = tid; i < 16 * 64; i += 256) {
        int ci = i >> 6; int co = i & 63;
        w[i] = W_w[co * 16 + ci];
    }
    int blk = blockIdx.x;                        // NB*256 blocks: one row y
    int n = blk >> 8, y = blk & 255;
    // phase 1: gather zi for pixel (y, x=tid)
    {
        int x = tid;
        int yp = y + 1, xp = x + 1;
        int lh1 = yp >> 2; if (lh1 > 63) lh1 = 63;
        int lh0 = (yp >= 3) ? ((yp - 3) >> 2) : 0;
        int lw1 = xp >> 2; if (lw1 > 63) lw1 = 63;
        int lw0 = (xp >= 3) ? ((xp - 3) >> 2) : 0;
        const unsigned short* a0 = aggb + (size_t)n * LL * DINP;
        float zic[16];
#pragma unroll
        for (int ci = 0; ci < 16; ci++) zic[ci] = 0.f;
        for (int lh = lh0; lh <= lh1; lh++) {
            int dy = yp - 4 * lh;
            for (int lw = lw0; lw <= lw1; lw++) {
                int dx = xp - 4 * lw;
                const unsigned short* ap = a0 + (size_t)(lh * 64 + lw) * DINP + dy * 7 + dx;
#pragma unroll
                for (int ci = 0; ci < 16; ci++)
                    zic[ci] += bf2f(ap[ci * 49]);
            }
        }
        float icnt = 1.f / (float)((lh1 - lh0 + 1) * (lw1 - lw0 + 1));
#pragma unroll
        for (int ci = 0; ci < 16; ci++) zl[ci][x] = zic[ci] * icnt;
    }
    __syncthreads();
    // phase 2: co-group x pixel-quad; all global traffic is float4
    int cg = tid >> 6;                           // co base cg*16
    int pq = tid & 63;                           // pixels pq*4 .. pq*4+3
    float4 acc[16];
#pragma unroll
    for (int k = 0; k < 16; k++) acc[k] = make_float4(0.f, 0.f, 0.f, 0.f);
#pragma unroll
    for (int ci = 0; ci < 16; ci++) {
        float4 z = *(const float4*)&zl[ci][pq * 4];
        const float* wrow = &w[ci * 64 + cg * 16];
#pragma unroll
        for (int k = 0; k < 16; k++) {
            float wv = wrow[k];
            acc[k].x += z.x * wv; acc[k].y += z.y * wv;
            acc[k].z += z.z * wv; acc[k].w += z.w * wv;
        }
    }
#pragma unroll
    for (int k = 0; k < 16; k++) {
        int co = cg * 16 + k;
        size_t base = (((size_t)n * 64 + co) << 16) + ((size_t)y << 8) + pq * 4;
        float4 bb = *(const float4*)&b[base];
        float wb = W_b[co];
        float4 o;
        o.x = bb.x + acc[k].x + wb; o.y = bb.y + acc[k].y + wb;
        o.z = bb.z + acc[k].z + wb; o.w = bb.w + acc[k].w + wb;
        *(float4*)&out[base] = o;
    }
}

extern "C" void kernel_launch(void* const* d_in, const int* in_sizes, int n_in,
                              void* d_out, int out_size, void* d_ws, size_t ws_size,
                              hipStream_t stream) {
    const float* b     = (const float*)d_in[0];
    const float* g_w   = (const float*)d_in[1];
    const float* g_b   = (const float*)d_in[2];
    const float* th_w  = (const float*)d_in[3];
    const float* th_b  = (const float*)d_in[4];
    const float* W_w   = (const float*)d_in[5];
    const float* W_b   = (const float*)d_in[6];
    const float* fc1_w = (const float*)d_in[7];
    const float* fc1_b = (const float*)d_in[8];
    const float* fc2_w = (const float*)d_in[9];
    const float* fc2_b = (const float*)d_in[10];
    const float* thr_w = (const float*)d_in[11];
    const float* thr_b = (const float*)d_in[12];
    // d_in[13], d_in[14] (bias conv): constant along softmax axis -> cancels.
    float* out = (float*)d_out;

    float* ws = (float*)d_ws;
    size_t off = 0;
    auto alloc = [&](size_t nf) { float* p = ws + off; off += (nf + 63) & ~(size_t)63; return p; };
    unsigned short* aggb = (unsigned short*)alloc((size_t)NB * LL * DINP / 2);
    unsigned short* bTp  = (unsigned short*)alloc((size_t)NB * YP * 8 * XP * 8 / 2);
    unsigned short* bx   = (unsigned short*)alloc((size_t)NB * HH * WWD * 32 / 2);
    unsigned short* Pb   = (unsigned short*)alloc((size_t)NB * LL * DKP / 2);
    unsigned char*  piT8 = (unsigned char*)alloc((size_t)NB * DINP * LL / 4);
    unsigned short* fcout = (unsigned short*)alloc((size_t)NB * 2 * LL * DOUTP / 2);
    unsigned short* wbt  = (unsigned short*)alloc(18432 / 2);
    unsigned short* fcwb = (unsigned short*)alloc((size_t)2 * DOUTP * DKP / 2);
    float* thr  = alloc((size_t)NB * LL);
    unsigned short* score = (unsigned short*)alloc((size_t)NB * LL * LL / 2);
    unsigned char*  attn8 = (unsigned char*)alloc((size_t)NB * LL * LL / 4);

    k_prep_b<<<dim3(NB * YP), 256, 0, stream>>>(b, bTp);
    k_prep_wb<<<dim3(72), 256, 0, stream>>>(g_w, th_w, wbt);
    k_prep_fc<<<dim3((2 * DOUTP * DKP + 255) / 256), 256, 0, stream>>>(fc1_w, fc2_w, fcwb);
    k_convm<<<dim3(NB * 256), 256, 0, stream>>>(bTp, wbt, g_b, th_b, bx);
    k_thr<<<dim3(2048), 256, 0, stream>>>(bTp, thr_w, thr_b, thr);
    k_patches<<<dim3(NB * 64 * 4), 256, 0, stream>>>(bx, Pb, piT8);
    // FC: wif/xif = relu(Pb @ fcwb^T + bias) -> fcout[z=n*2+f][4096][256] bf16
    k_gemm_nt<2><<<dim3(256), 256, 0, stream>>>(
        Pb, fcwb, (void*)fcout, DKP, DKP, DOUTP, DKP,
        (size_t)LL * DKP, (size_t)DOUTP * DKP, (size_t)LL * DOUTP, fc1_b, fc2_b, 32, 2);
    // score[l][m] = wif[l].xif[m]  (bf16 out)
    k_gemm_nt<1><<<dim3(2048), 256, 0, stream>>>(
        fcout, fcout + (size_t)LL * DOUTP, (void*)score, DOUTP, DOUTP, LL, DOUTP,
        (size_t)2 * LL * DOUTP, (size_t)2 * LL * DOUTP, (size_t)LL * LL, nullptr, nullptr, 32, 32);
    k_softmax<<<dim3(NB * LL), 256, 0, stream>>>(score, thr, attn8);
    // agg[l][d] = sum_m attn8[l][m] * piT8[d][m]  (MX fp8, unit scale, bf16 out)
    // 256x128 tiles: grid (4096/256)x(896/128)x2 = 224 (%8==0 for swizzle)
    k_gemm_mx<<<dim3(224), 256, 0, stream>>>(
        attn8, piT8, aggb, LL, LL, DINP, LL,
        (size_t)LL * LL, (size_t)DINP * LL, (size_t)LL * DINP, 16, 7);
    k_fold_final<<<dim3(NB * 256), 256, 0, stream>>>(aggb, b, W_w, W_b, out);
}

// Round 9
// 291.601 us; speedup vs baseline: 1.0340x; 1.0340x over previous
//
#include <hip/hip_runtime.h>
#include <math.h>

#define CIN  64
#define CI   16
#define HH   256
#define WWD  256
#define KS   7
#define STR  4
#define LH   64
#define LWD  64
#define LL   4096
#define DIN  784
#define DINP 896     // padded to multiple of 128 (agg N)
#define DKP  832     // DIN padded to multiple of 64 (fc K)
#define DOUT 196
#define DOUTP 256    // padded N for fc / K for score GEMM
#define NB   2
#define YP   258     // padded rows in bTp
#define XP   264     // padded cols in bTp

typedef __attribute__((ext_vector_type(8))) short bf16x8;
typedef __attribute__((ext_vector_type(4))) float f32x4;
typedef __attribute__((ext_vector_type(16))) float f32x16;
typedef __attribute__((ext_vector_type(8))) int i32x8;
typedef __attribute__((ext_vector_type(4))) int i32x4;

__device__ __forceinline__ unsigned short f2bf(float x) {
    unsigned int u = __float_as_uint(x);
    unsigned int r = (u + 0x7FFFu + ((u >> 16) & 1u)) >> 16;
    return (unsigned short)r;
}
__device__ __forceinline__ float bf2f(unsigned short h) {
    return __uint_as_float(((unsigned int)h) << 16);
}

__device__ __forceinline__ void stage16(const void* g, void* l) {
#if defined(__has_builtin)
#if __has_builtin(__builtin_amdgcn_global_load_lds)
    __builtin_amdgcn_global_load_lds(
        (const __attribute__((address_space(1))) unsigned int*)g,
        (__attribute__((address_space(3))) unsigned int*)l, 16, 0, 0);
    return;
#endif
#endif
    *(float4*)l = *(const float4*)g;
}

// XCD-aware bijective swizzle of a flat 1-D grid (total % 8 == 0).
__device__ __forceinline__ void swz_grid(int gx, int gy, int& ib, int& jb, int& zb) {
    int total = gridDim.x;
    int flat = blockIdx.x;
    int s = (flat & 7) * (total >> 3) + (flat >> 3);
    ib = s % gx; int rem = s / gx; jb = rem % gy; zb = rem / gy;
}

// ---- prep: b (fp32 NCHW) -> bTp bf16 [n][y+1][s=ci/8][x+4][j=ci%8], padded -
__global__ __launch_bounds__(256) void k_prep_b(const float* __restrict__ b,
                                                unsigned short* __restrict__ bTp) {
    int blk = blockIdx.x;            // n*YP blocks
    int yy = blk % YP, n = blk / YP;
    int y = yy - 1;
    int tid = threadIdx.x;
    int s = tid >> 5, cq = tid & 31;
    bool yv = (y >= 0 && y < 256);
#pragma unroll
    for (int it = 0; it < 3; it++) {
        int c = it * 32 + cq;
        if (c < 66) {
            int xx0 = c * 4, x0 = xx0 - 4;
            unsigned short h[4][8];
            if (yv && x0 >= 0 && x0 + 3 < 256) {
#pragma unroll
                for (int j = 0; j < 8; j++) {
                    float4 f = *(const float4*)&b[((size_t)(n * 64 + s * 8 + j) * 256 + y) * 256 + x0];
                    h[0][j] = f2bf(f.x); h[1][j] = f2bf(f.y);
                    h[2][j] = f2bf(f.z); h[3][j] = f2bf(f.w);
                }
            } else {
#pragma unroll
                for (int k = 0; k < 4; k++) {
                    int x = x0 + k;
                    bool v = yv && x >= 0 && x < 256;
#pragma unroll
                    for (int j = 0; j < 8; j++)
                        h[k][j] = v ? f2bf(b[((size_t)(n * 64 + s * 8 + j) * 256 + y) * 256 + x])
                                    : (unsigned short)0;
                }
            }
#pragma unroll
            for (int k = 0; k < 4; k++)
                *(uint4*)&bTp[((((size_t)n * YP + yy) * 8 + s) * XP + xx0 + k) * 8] = *(uint4*)h[k];
        }
    }
}

// ---- prep: conv weights -> wbt[t][h][q][co32][j8] bf16 ---------------------
__global__ void k_prep_wb(const float* __restrict__ g_w, const float* __restrict__ th_w,
                          unsigned short* __restrict__ wbt) {
    int i = blockIdx.x * 256 + threadIdx.x;
    if (i >= 18432) return;
    int j = i & 7, co = (i >> 3) & 31, q = (i >> 8) & 3, h = (i >> 10) & 1, t = i >> 11;
    int ci = h * 32 + q * 8 + j;
    float v;
    if (co < 16) v = g_w[((size_t)co * 64 + ci) * 9 + t];
    else         v = (t == 4) ? th_w[(size_t)(co - 16) * 64 + ci] : 0.f;
    wbt[i] = f2bf(v);
}

// ---- prep: fc weights -> bf16 [f][256][832], zero-padded -------------------
__global__ void k_prep_fc(const float* __restrict__ fc1_w, const float* __restrict__ fc2_w,
                          unsigned short* __restrict__ fcwb) {
    int i = blockIdx.x * 256 + threadIdx.x;
    if (i >= 2 * DOUTP * DKP) return;
    int col = i % DKP; int row = (i / DKP) % DOUTP; int f = i / (DKP * DOUTP);
    float v = 0.f;
    if (row < DOUT && col < DIN) v = (f ? fc2_w : fc1_w)[row * DIN + col];
    fcwb[i] = f2bf(v);
}

// ---- MFMA implicit-GEMM conv: bx[n][y][x][co32] ----------------------------
__global__ __launch_bounds__(256) void k_convm(
        const unsigned short* __restrict__ bTp, const unsigned short* __restrict__ wbt,
        const float* __restrict__ g_b, const float* __restrict__ th_b,
        unsigned short* __restrict__ bx) {
    __shared__ unsigned short wb[18432];
    __shared__ unsigned short ti[8 * 3 * 68 * 8];
    int tid = threadIdx.x;
#pragma unroll
    for (int i = 0; i < 9; i++) {
        int c = i * 256 + tid;
        stage16(wbt + (size_t)c * 8, &wb[c * 8]);
    }
    int n = blockIdx.x >> 8, y = blockIdx.x & 255;
    int wave = tid >> 6, lane = tid & 63, lr = lane & 15, q = lane >> 4;
    int m0 = wave * 16;
    float bg = g_b[lr], bt = th_b[lr];
    for (int xs = 0; xs < 4; xs++) {
        __syncthreads();
        int x0 = xs * 64;
#pragma unroll
        for (int i = 0; i < 7; i++) {
            int c = i * 256 + tid;
            if (c < 1632) {
                int s = c / 204; int rem = c % 204; int r = rem / 68; int cc = rem % 68;
                const unsigned short* src =
                    bTp + ((((size_t)n * YP + y + r) * 8 + s) * XP + (x0 + 3 + cc)) * 8;
                stage16(src, &ti[c * 8]);
            }
        }
        __syncthreads();
        f32x4 a0 = {bg, bg, bg, bg}, a1 = {bt, bt, bt, bt};
#pragma unroll
        for (int t = 0; t < 9; t++) {
            int dy = t / 3, dx = t % 3;
#pragma unroll
            for (int h = 0; h < 2; h++) {
                int s = h * 4 + q;
                bf16x8 av = *(const bf16x8*)&ti[(((s * 3 + dy) * 68) + m0 + lr + dx) * 8];
                bf16x8 b0 = *(const bf16x8*)&wb[((((t * 2 + h) * 4 + q) * 32) + lr) * 8];
                bf16x8 b1 = *(const bf16x8*)&wb[((((t * 2 + h) * 4 + q) * 32) + 16 + lr) * 8];
                a0 = __builtin_amdgcn_mfma_f32_16x16x32_bf16(av, b0, a0, 0, 0, 0);
                a1 = __builtin_amdgcn_mfma_f32_16x16x32_bf16(av, b1, a1, 0, 0, 0);
            }
        }
        size_t pb = (((size_t)n * 256 + y) * 256 + x0 + m0 + q * 4);
#pragma unroll
        for (int r = 0; r < 4; r++) {
            bx[(pb + r) * 32 + lr]      = f2bf(a0[r]);
            bx[(pb + r) * 32 + 16 + lr] = f2bf(a1[r]);
        }
    }
}

// ---- thr: 7x7 stride-4 conv from bf16 bTp; wave per output, lane=(s,j)=ci --
__global__ __launch_bounds__(256) void k_thr(
        const unsigned short* __restrict__ bTp, const float* __restrict__ thr_w,
        const float* __restrict__ thr_b, float* __restrict__ thr) {
    __shared__ float w[64 * 49];
    int tid = threadIdx.x;
    for (int i = tid; i < 64 * 49; i += 256) w[i] = thr_w[i];
    __syncthreads();
    int wid = (blockIdx.x << 2) + (tid >> 6);
    int lane = tid & 63;
    int s = lane >> 3, j = lane & 7;
    int n = wid >> 12, l = wid & 4095;
    int lh = (l >> 6), lw = l & 63;
    const float* wl = w + (s * 8 + j) * 49;
    float acc = 0.f;
#pragma unroll
    for (int dy = 0; dy < 7; dy++) {
        int yy = lh * 4 + dy;
        if (yy >= YP) continue;
        const unsigned short* row = bTp + (((size_t)(n * YP + yy) * 8 + s) * XP) * 8;
#pragma unroll
        for (int dx = 0; dx < 7; dx++) {
            int xx = lw * 4 + dx + 3;
            acc = fmaf(bf2f(row[xx * 8 + j]), wl[dy * 7 + dx], acc);
        }
    }
#pragma unroll
    for (int off = 32; off > 0; off >>= 1) acc += __shfl_down(acc, off, 64);
    if (lane == 0) thr[wid] = acc + thr_b[0];
}

// ---- fused patch extraction: bx -> Pb (bf16, [n][l][DKP]) and
// ----                         bx -> piT8 (fp8, [n][DINP][l])
__global__ __launch_bounds__(256) void k_patches(
        const unsigned short* __restrict__ bx,
        unsigned short* __restrict__ Pb, unsigned char* __restrict__ piT8) {
    __shared__ unsigned short sh[7][68][32];     // 30464 B
    int tid = threadIdx.x;
    int blk = blockIdx.x;                        // n*64*4
    int lwg = blk & 3, lh = (blk >> 2) & 63, n = blk >> 8;
    int x0 = lwg * 64 - 1;                       // (lwg*16)*4 - 1
    int y0 = lh * 4 - 1;
    // stage: 7 rows x 68 cols x 32 ci = 1904 chunks of 16B, zero-filled OOB
    for (int it = 0; it < 8; it++) {
        int c = it * 256 + tid;
        if (c < 1904) {
            int q = c & 3, xx = (c >> 2) % 68, r = c / 272;
            int y = y0 + r, x = x0 + xx;
            uint4 v = make_uint4(0u, 0u, 0u, 0u);
            if (y >= 0 && y < 256 && x >= 0 && x < 256)
                v = *(const uint4*)&bx[(((size_t)(n * 256 + y) * 256 + x) * 32) + q * 8];
            *(uint4*)&sh[r][xx][q * 8] = v;
        }
    }
    __syncthreads();
    // emit Pb: 16 l x 104 uint4 (8 bf16 each), d >= DIN zero-padded
    for (int it = 0; it < 7; it++) {
        int idx = it * 256 + tid;
        if (idx < 16 * 104) {
            int lwl = idx / 104, v8 = idx % 104;
            unsigned short o[8];
#pragma unroll
            for (int k = 0; k < 8; k++) {
                int d = v8 * 8 + k;
                unsigned short val = 0;
                if (d < DIN) {
                    int ci = d / 49, t = d % 49, dy = t / 7, dx = t % 7;
                    val = sh[dy][lwl * 4 + dx][ci];
                }
                o[k] = val;
            }
            int l = lh * 64 + lwg * 16 + lwl;
            *(uint4*)&Pb[((size_t)n * LL + l) * DKP + v8 * 8] = *(uint4*)o;
        }
    }
    // emit piT8: for each d (incl. zero pad to DINP), 16 consecutive l bytes
    for (int it = 0; it < 4; it++) {
        int d = it * 256 + tid;
        if (d < DINP) {
            unsigned int w[4] = {0u, 0u, 0u, 0u};
            if (d < DIN) {
                int ci = d / 49, t = d % 49, dy = t / 7, dx = t % 7;
#pragma unroll
                for (int p = 0; p < 4; p++) {
                    float v0 = bf2f(sh[dy][(p * 4 + 0) * 4 + dx][16 + ci]);
                    float v1 = bf2f(sh[dy][(p * 4 + 1) * 4 + dx][16 + ci]);
                    float v2 = bf2f(sh[dy][(p * 4 + 2) * 4 + dx][16 + ci]);
                    float v3 = bf2f(sh[dy][(p * 4 + 3) * 4 + dx][16 + ci]);
                    int a = __builtin_amdgcn_cvt_pk_fp8_f32(v0, v1, 0, false);
                    a     = __builtin_amdgcn_cvt_pk_fp8_f32(v2, v3, a, true);
                    w[p] = (unsigned)a;
                }
            }
            *(uint4*)&piT8[((size_t)n * DINP + d) * LL + lh * 64 + lwg * 16] =
                make_uint4(w[0], w[1], w[2], w[3]);
        }
    }
}

// ---- MFMA GEMM (NT) bf16, depth-2 pipelined (T3+T4), XCD-swizzled: --------
template<int MODE>
__global__ __launch_bounds__(256) void k_gemm_nt(
        const unsigned short* __restrict__ A, const unsigned short* __restrict__ Bt,
        void* __restrict__ C, int lda, int ldb, int ldc, int K,
        size_t sA, size_t sB, size_t sC,
        const float* __restrict__ bias1, const float* __restrict__ bias2,
        int gx, int gy) {
    __shared__ unsigned short lA[2][128 * 64];
    __shared__ unsigned short lB[2][128 * 64];
    int tid = threadIdx.x;
    int wave = tid >> 6, lane = tid & 63;
    int lr = lane & 15, lq = lane >> 4;
    int wm = (wave >> 1) * 64, wn = (wave & 1) * 64;
    int ib, jb, z;
    swz_grid(gx, gy, ib, jb, z);
    int i0 = ib * 128, j0 = jb * 128;
    int az = (MODE == 2) ? (z >> 1) : z;
    int bz = (MODE == 2) ? (z & 1) : z;
    const unsigned short* Ab = A + (size_t)az * sA + (size_t)i0 * lda;
    const unsigned short* Bb = Bt + (size_t)bz * sB + (size_t)j0 * ldb;

    auto stageAB = [&](int buf, int k0) {
#pragma unroll
        for (int it = 0; it < 4; it++) {
            int c = it * 256 + tid;
            int row = c >> 3, slot = c & 7;
            int col8 = slot ^ (row & 7);
            stage16(Ab + (size_t)row * lda + k0 + col8 * 8, &lA[buf][c * 8]);
        }
#pragma unroll
        for (int it = 0; it < 4; it++) {
            int c = it * 256 + tid;
            int row = c >> 3, slot = c & 7;
            int col8 = slot ^ (row & 7);
            stage16(Bb + (size_t)row * ldb + k0 + col8 * 8, &lB[buf][c * 8]);
        }
    };

    f32x4 acc[4][4] = {};
    int NT = K >> 6;
    stageAB(0, 0);
    stageAB(1, 64);
    for (int t = 0; t < NT; ++t) {
        int cur = t & 1;
        if (t + 1 < NT) { asm volatile("s_waitcnt vmcnt(8)" ::: "memory"); }
        else            { asm volatile("s_waitcnt vmcnt(0)" ::: "memory"); }
        __builtin_amdgcn_s_barrier();
#pragma unroll
        for (int ks = 0; ks < 2; ks++) {
            bf16x8 af[4], bfr[4];
#pragma unroll
            for (int t2 = 0; t2 < 4; t2++) {
                int row = wm + t2 * 16 + lr;
                int slot = ks * 4 + lq;
                af[t2] = *(const bf16x8*)&lA[cur][row * 64 + (slot ^ (row & 7)) * 8];
            }
#pragma unroll
            for (int t2 = 0; t2 < 4; t2++) {
                int row = wn + t2 * 16 + lr;
                int slot = ks * 4 + lq;
                bfr[t2] = *(const bf16x8*)&lB[cur][row * 64 + (slot ^ (row & 7)) * 8];
            }
#pragma unroll
            for (int mi = 0; mi < 4; mi++)
#pragma unroll
                for (int nj = 0; nj < 4; nj++)
                    acc[mi][nj] = __builtin_amdgcn_mfma_f32_16x16x32_bf16(
                        af[mi], bfr[nj], acc[mi][nj], 0, 0, 0);
        }
        asm volatile("s_waitcnt lgkmcnt(0)" ::: "memory");
        __builtin_amdgcn_s_barrier();
        if (t + 2 < NT) stageAB(cur, (t + 2) << 6);
    }
    if (MODE == 1) {
        unsigned short* Cb = (unsigned short*)C + (size_t)z * sC;
#pragma unroll
        for (int mi = 0; mi < 4; mi++)
#pragma unroll
            for (int r = 0; r < 4; r++) {
                int row = i0 + wm + mi * 16 + lq * 4 + r;
#pragma unroll
                for (int nj = 0; nj < 4; nj++)
                    Cb[(size_t)row * ldc + j0 + wn + nj * 16 + lr] = f2bf(acc[mi][nj][r]);
            }
    } else {
        const float* biasp = bz ? bias2 : bias1;
        unsigned short* Cb = (unsigned short*)C + (size_t)z * sC;
#pragma unroll
        for (int mi = 0; mi < 4; mi++)
#pragma unroll
            for (int r = 0; r < 4; r++) {
                int row = i0 + wm + mi * 16 + lq * 4 + r;
#pragma unroll
                for (int nj = 0; nj < 4; nj++) {
                    int col = j0 + wn + nj * 16 + lr;
                    float bv = (col < DOUT) ? biasp[col] : 0.f;
                    float v = fmaxf(acc[mi][nj][r] + bv, 0.f);
                    Cb[(size_t)row * ldc + col] = f2bf(v);
                }
            }
    }
}

// ---- MX-fp8 MFMA GEMM (NT), depth-2 pipelined, XCD-swizzled ----------------
// 128x128 tile, BK=128 bytes, 4 waves 2x2, wave=64x64 as 2x2 of 32x32x64.
// (Reverted from 256x128: wide tile gave only 1.33x FLOP/read and dropped to
//  1 wave/SIMD, exposing all ds_read->MFMA latency. 128^2 @2 blocks/CU wins.)
__global__ __launch_bounds__(256) void k_gemm_mx(
        const unsigned char* __restrict__ A, const unsigned char* __restrict__ Bt,
        unsigned short* __restrict__ C, int lda, int ldb, int ldc, int K,
        size_t sA, size_t sB, size_t sC, int gx, int gy) {
    __shared__ unsigned char lA[2][128 * 128];
    __shared__ unsigned char lB[2][128 * 128];
    int tid = threadIdx.x;
    int wave = tid >> 6, lane = tid & 63;
    int lr = lane & 31, hf = lane >> 5;
    int wm = (wave >> 1) * 64, wn = (wave & 1) * 64;
    int ib, jb, z;
    swz_grid(gx, gy, ib, jb, z);
    int i0 = ib * 128, j0 = jb * 128;
    const unsigned char* Ab = A + (size_t)z * sA + (size_t)i0 * lda;
    const unsigned char* Bb = Bt + (size_t)z * sB + (size_t)j0 * ldb;

    auto stageAB = [&](int buf, int k0) {
#pragma unroll
        for (int it = 0; it < 4; it++) {          // A: 1024 chunks of 16B
            int c = it * 256 + tid;
            int row = c >> 3, slot = c & 7;
            int col16 = slot ^ ((row ^ (row >> 3)) & 7);
            stage16(Ab + (size_t)row * lda + k0 + col16 * 16, &lA[buf][c * 16]);
        }
#pragma unroll
        for (int it = 0; it < 4; it++) {          // B: 1024 chunks of 16B
            int c = it * 256 + tid;
            int row = c >> 3, slot = c & 7;
            int col16 = slot ^ ((row ^ (row >> 3)) & 7);
            stage16(Bb + (size_t)row * ldb + k0 + col16 * 16, &lB[buf][c * 16]);
        }
    };

    f32x16 acc[2][2] = {};
    int NT = K >> 7;
    stageAB(0, 0);
    stageAB(1, 128);
    for (int t = 0; t < NT; ++t) {
        int cur = t & 1;
        // wait for buf[cur]'s 8 per-wave loads; keep next tile's 8 in flight
        if (t + 1 < NT) { asm volatile("s_waitcnt vmcnt(8)" ::: "memory"); }
        else           { asm volatile("s_waitcnt vmcnt(0)" ::: "memory"); }
        __builtin_amdgcn_s_barrier();
        asm volatile("" ::: "memory");
#pragma unroll
        for (int kk = 0; kk < 2; kk++) {          // two K=64 steps
            i32x8 af[2], bfv[2];
            int c0 = kk * 4 + hf * 2;
#pragma unroll
            for (int t2 = 0; t2 < 2; t2++) {
                int row = wm + t2 * 32 + lr;
                int sw = (row ^ (row >> 3)) & 7;
                i32x4 lo = *(const i32x4*)&lA[cur][row * 128 + ((c0    ) ^ sw) * 16];
                i32x4 hi = *(const i32x4*)&lA[cur][row * 128 + ((c0 + 1) ^ sw) * 16];
                af[t2][0] = lo[0]; af[t2][1] = lo[1]; af[t2][2] = lo[2]; af[t2][3] = lo[3];
                af[t2][4] = hi[0]; af[t2][5] = hi[1]; af[t2][6] = hi[2]; af[t2][7] = hi[3];
            }
#pragma unroll
            for (int t2 = 0; t2 < 2; t2++) {
                int row = wn + t2 * 32 + lr;
                int sw = (row ^ (row >> 3)) & 7;
                i32x4 lo = *(const i32x4*)&lB[cur][row * 128 + ((c0    ) ^ sw) * 16];
                i32x4 hi = *(const i32x4*)&lB[cur][row * 128 + ((c0 + 1) ^ sw) * 16];
                bfv[t2][0] = lo[0]; bfv[t2][1] = lo[1]; bfv[t2][2] = lo[2]; bfv[t2][3] = lo[3];
                bfv[t2][4] = hi[0]; bfv[t2][5] = hi[1]; bfv[t2][6] = hi[2]; bfv[t2][7] = hi[3];
            }
#pragma unroll
            for (int mi = 0; mi < 2; mi++)
#pragma unroll
                for (int nj = 0; nj < 2; nj++)
                    acc[mi][nj] = __builtin_amdgcn_mfma_scale_f32_32x32x64_f8f6f4(
                        af[mi], bfv[nj], acc[mi][nj],
                        0, 0,                      // cbsz = fp8(e4m3), blgp = fp8(e4m3)
                        0, 0x7F7F7F7F,             // opsel_a, scale_a = 1.0
                        0, 0x7F7F7F7F);            // opsel_b, scale_b = 1.0
        }
        // all ds_reads of buf[cur] complete before anyone restages into it
        asm volatile("s_waitcnt lgkmcnt(0)" ::: "memory");
        __builtin_amdgcn_s_barrier();
        if (t + 2 < NT) stageAB(cur, (t + 2) << 7);
    }
    unsigned short* Cb = C + (size_t)z * sC;
#pragma unroll
    for (int mi = 0; mi < 2; mi++)
#pragma unroll
        for (int nj = 0; nj < 2; nj++)
#pragma unroll
            for (int reg = 0; reg < 16; reg++) {
                int row = i0 + wm + mi * 32 + (reg & 3) + 8 * (reg >> 2) + 4 * hf;
                int col = j0 + wn + nj * 32 + lr;
                Cb[(size_t)row * ldc + col] = f2bf(acc[mi][nj][reg]);
            }
}

// ---- fused masked-softmax: bf16 score row -> fp8 attn row (regs + shfl) ----
__global__ __launch_bounds__(256) void k_softmax(
        const unsigned short* __restrict__ score, const float* __restrict__ thr,
        unsigned char* __restrict__ attn8) {
    __shared__ float redm[4], reds[4], redn[4];
    int row = blockIdx.x, tid = threadIdx.x;
    int wave = tid >> 6, lane = tid & 63;
    const uint4* g4 = (const uint4*)(score + (size_t)row * LL);
    float t = thr[row];
    uint4 u0 = g4[tid], u1 = g4[tid + 256];
    float v[16];
    {
        unsigned int w[8] = {u0.x, u0.y, u0.z, u0.w, u1.x, u1.y, u1.z, u1.w};
#pragma unroll
        for (int q = 0; q < 8; q++) {
            v[2 * q]     = __uint_as_float(w[q] << 16);
            v[2 * q + 1] = __uint_as_float(w[q] & 0xFFFF0000u);
        }
    }
    float mx = 0.f;
#pragma unroll
    for (int k = 0; k < 16; k++) if (v[k] >= t) mx = fmaxf(mx, v[k]);
#pragma unroll
    for (int off = 32; off > 0; off >>= 1) mx = fmaxf(mx, __shfl_xor(mx, off, 64));
    if (lane == 0) redm[wave] = mx;
    __syncthreads();
    float M = 10.f * fmaxf(fmaxf(fmaxf(redm[0], redm[1]), fmaxf(redm[2], redm[3])), 0.f);
    float e[16];
    float s2 = 0.f, n0 = 0.f;
#pragma unroll
    for (int k = 0; k < 16; k++) {
        if (v[k] >= t) { e[k] = __expf(10.f * v[k] - M); s2 += e[k]; }
        else           { e[k] = 0.f; n0 += 1.f; }
    }
#pragma unroll
    for (int off = 32; off > 0; off >>= 1) {
        s2 += __shfl_xor(s2, off, 64);
        n0 += __shfl_xor(n0, off, 64);
    }
    if (lane == 0) { reds[wave] = s2; redn[wave] = n0; }
    __syncthreads();
    float S2 = (reds[0] + reds[1]) + (reds[2] + reds[3]);
    float N0 = (redn[0] + redn[1]) + (redn[2] + redn[3]);
    float iD = 1.f / (S2 + 1e-8f * (S2 + N0 * __expf(-M)));
#pragma unroll
    for (int i = 0; i < 2; i++) {
        int c = tid + i * 256;
        int d0 = __builtin_amdgcn_cvt_pk_fp8_f32(e[i * 8 + 0] * iD, e[i * 8 + 1] * iD, 0, false);
        d0     = __builtin_amdgcn_cvt_pk_fp8_f32(e[i * 8 + 2] * iD, e[i * 8 + 3] * iD, d0, true);
        int d1 = __builtin_amdgcn_cvt_pk_fp8_f32(e[i * 8 + 4] * iD, e[i * 8 + 5] * iD, 0, false);
        d1     = __builtin_amdgcn_cvt_pk_fp8_f32(e[i * 8 + 6] * iD, e[i * 8 + 7] * iD, d1, true);
        *(uint2*)&attn8[(size_t)row * LL + (size_t)c * 8] = make_uint2((unsigned)d0, (unsigned)d1);
    }
}

// ---- fused fold+final, vectorized: phase 1 gathers zi row into LDS;
// ---- phase 2 does 16->64 conv + residual with float4 streams (1KB/wave).
__global__ __launch_bounds__(256) void k_fold_final(
        const unsigned short* __restrict__ aggb, const float* __restrict__ b,
        const float* __restrict__ W_w, const float* __restrict__ W_b,
        float* __restrict__ out) {
    __shared__ float w[16 * 64];
    __shared__ float zl[16][260];                // padded row: conflict-free
    int tid = threadIdx.x;
    for (int i = tid; i < 16 * 64; i += 256) {
        int ci = i >> 6; int co = i & 63;
        w[i] = W_w[co * 16 + ci];
    }
    int blk = blockIdx.x;                        // NB*256 blocks: one row y
    int n = blk >> 8, y = blk & 255;
    // phase 1: gather zi for pixel (y, x=tid)
    {
        int x = tid;
        int yp = y + 1, xp = x + 1;
        int lh1 = yp >> 2; if (lh1 > 63) lh1 = 63;
        int lh0 = (yp >= 3) ? ((yp - 3) >> 2) : 0;
        int lw1 = xp >> 2; if (lw1 > 63) lw1 = 63;
        int lw0 = (xp >= 3) ? ((xp - 3) >> 2) : 0;
        const unsigned short* a0 = aggb + (size_t)n * LL * DINP;
        float zic[16];
#pragma unroll
        for (int ci = 0; ci < 16; ci++) zic[ci] = 0.f;
        for (int lh = lh0; lh <= lh1; lh++) {
            int dy = yp - 4 * lh;
            for (int lw = lw0; lw <= lw1; lw++) {
                int dx = xp - 4 * lw;
                const unsigned short* ap = a0 + (size_t)(lh * 64 + lw) * DINP + dy * 7 + dx;
#pragma unroll
                for (int ci = 0; ci < 16; ci++)
                    zic[ci] += bf2f(ap[ci * 49]);
            }
        }
        float icnt = 1.f / (float)((lh1 - lh0 + 1) * (lw1 - lw0 + 1));
#pragma unroll
        for (int ci = 0; ci < 16; ci++) zl[ci][x] = zic[ci] * icnt;
    }
    __syncthreads();
    // phase 2: co-group x pixel-quad; all global traffic is float4
    int cg = tid >> 6;                           // co base cg*16
    int pq = tid & 63;                           // pixels pq*4 .. pq*4+3
    float4 acc[16];
#pragma unroll
    for (int k = 0; k < 16; k++) acc[k] = make_float4(0.f, 0.f, 0.f, 0.f);
#pragma unroll
    for (int ci = 0; ci < 16; ci++) {
        float4 z = *(const float4*)&zl[ci][pq * 4];
        const float* wrow = &w[ci * 64 + cg * 16];
#pragma unroll
        for (int k = 0; k < 16; k++) {
            float wv = wrow[k];
            acc[k].x += z.x * wv; acc[k].y += z.y * wv;
            acc[k].z += z.z * wv; acc[k].w += z.w * wv;
        }
    }
#pragma unroll
    for (int k = 0; k < 16; k++) {
        int co = cg * 16 + k;
        size_t base = (((size_t)n * 64 + co) << 16) + ((size_t)y << 8) + pq * 4;
        float4 bb = *(const float4*)&b[base];
        float wb = W_b[co];
        float4 o;
        o.x = bb.x + acc[k].x + wb; o.y = bb.y + acc[k].y + wb;
        o.z = bb.z + acc[k].z + wb; o.w = bb.w + acc[k].w + wb;
        *(float4*)&out[base] = o;
    }
}

extern "C" void kernel_launch(void* const* d_in, const int* in_sizes, int n_in,
                              void* d_out, int out_size, void* d_ws, size_t ws_size,
                              hipStream_t stream) {
    const float* b     = (const float*)d_in[0];
    const float* g_w   = (const float*)d_in[1];
    const float* g_b   = (const float*)d_in[2];
    const float* th_w  = (const float*)d_in[3];
    const float* th_b  = (const float*)d_in[4];
    const float* W_w   = (const float*)d_in[5];
    const float* W_b   = (const float*)d_in[6];
    const float* fc1_w = (const float*)d_in[7];
    const float* fc1_b = (const float*)d_in[8];
    const float* fc2_w = (const float*)d_in[9];
    const float* fc2_b = (const float*)d_in[10];
    const float* thr_w = (const float*)d_in[11];
    const float* thr_b = (const float*)d_in[12];
    // d_in[13], d_in[14] (bias conv): constant along softmax axis -> cancels.
    float* out = (float*)d_out;

    float* ws = (float*)d_ws;
    size_t off = 0;
    auto alloc = [&](size_t nf) { float* p = ws + off; off += (nf + 63) & ~(size_t)63; return p; };
    unsigned short* aggb = (unsigned short*)alloc((size_t)NB * LL * DINP / 2);
    unsigned short* bTp  = (unsigned short*)alloc((size_t)NB * YP * 8 * XP * 8 / 2);
    unsigned short* bx   = (unsigned short*)alloc((size_t)NB * HH * WWD * 32 / 2);
    unsigned short* Pb   = (unsigned short*)alloc((size_t)NB * LL * DKP / 2);
    unsigned char*  piT8 = (unsigned char*)alloc((size_t)NB * DINP * LL / 4);
    unsigned short* fcout = (unsigned short*)alloc((size_t)NB * 2 * LL * DOUTP / 2);
    unsigned short* wbt  = (unsigned short*)alloc(18432 / 2);
    unsigned short* fcwb = (unsigned short*)alloc((size_t)2 * DOUTP * DKP / 2);
    float* thr  = alloc((size_t)NB * LL);
    unsigned short* score = (unsigned short*)alloc((size_t)NB * LL * LL / 2);
    unsigned char*  attn8 = (unsigned char*)alloc((size_t)NB * LL * LL / 4);

    k_prep_b<<<dim3(NB * YP), 256, 0, stream>>>(b, bTp);
    k_prep_wb<<<dim3(72), 256, 0, stream>>>(g_w, th_w, wbt);
    k_prep_fc<<<dim3((2 * DOUTP * DKP + 255) / 256), 256, 0, stream>>>(fc1_w, fc2_w, fcwb);
    k_convm<<<dim3(NB * 256), 256, 0, stream>>>(bTp, wbt, g_b, th_b, bx);
    k_thr<<<dim3(2048), 256, 0, stream>>>(bTp, thr_w, thr_b, thr);
    k_patches<<<dim3(NB * 64 * 4), 256, 0, stream>>>(bx, Pb, piT8);
    // FC: wif/xif = relu(Pb @ fcwb^T + bias) -> fcout[z=n*2+f][4096][256] bf16
    k_gemm_nt<2><<<dim3(256), 256, 0, stream>>>(
        Pb, fcwb, (void*)fcout, DKP, DKP, DOUTP, DKP,
        (size_t)LL * DKP, (size_t)DOUTP * DKP, (size_t)LL * DOUTP, fc1_b, fc2_b, 32, 2);
    // score[l][m] = wif[l].xif[m]  (bf16 out)
    k_gemm_nt<1><<<dim3(2048), 256, 0, stream>>>(
        fcout, fcout + (size_t)LL * DOUTP, (void*)score, DOUTP, DOUTP, LL, DOUTP,
        (size_t)2 * LL * DOUTP, (size_t)2 * LL * DOUTP, (size_t)LL * LL, nullptr, nullptr, 32, 32);
    k_softmax<<<dim3(NB * LL), 256, 0, stream>>>(score, thr, attn8);
    // agg[l][d] = sum_m attn8[l][m] * piT8[d][m]  (MX fp8, unit scale, bf16 out)
    k_gemm_mx<<<dim3(448), 256, 0, stream>>>(
        attn8, piT8, aggb, LL, LL, DINP, LL,
        (size_t)LL * LL, (size_t)DINP * LL, (size_t)LL * DINP, 32, 7);
    k_fold_final<<<dim3(NB * 256), 256, 0, stream>>>(aggb, b, W_w, W_b, out);
}